// Round 9
// baseline (236.279 us; speedup 1.0000x reference)
//
#include <hip/hip_runtime.h>

// MessageFunc: out[e,o] = sum_i (relu-MLP(e_vw)[e] . W2[32o+i] + b2[32o+i]) * hw[e,i]
// hw[e,i] = h_w[b, (32*kn+i)//20], e = b*20+kn. For fixed kn, (32*kn+i)//20 takes
// 2..3 values -> grouped W2g[kn][g][o][k] (<=96 cols instead of 1024).
//
// R9 = R8 + __launch_bounds__(256,3): R8 proved the allocator expands to fill
// whatever budget exists (VGPR stuck at 184 after evicting 32 regs of arrays),
// so the only way to 3 waves/SIMD (12 waves/CU) is an explicit cap of 512/3=170.
// Manual e_vw/hwg prefetch removed (~12 live regs) to make the 168 budget fit;
// at 12 waves/CU TLP replaces the manual pipeline. LDS 53.2KB -> 3 blocks/CU.
// Failure signature to watch: FETCH >> 15.5MB means the cap forced scratch spill.

typedef __bf16 bf16x8 __attribute__((ext_vector_type(8)));
typedef float  f32x4  __attribute__((ext_vector_type(4)));

#define NB       10000
#define NNEIGH   20
#define PADH     136       // padded LDS row: 272 B = 17 uint4; bank step 4 -> 2-way (free)
#define NCHUNK   39        // blocks per kn; 20*39=780 blocks ~= 3/CU; 4-5 btiles each

// ws layout (bytes)
#define WS_W0S   0         // bf16 [8][64][8]  A-frag-swizzled W0a (K=32, col16=b0)   8192 B
#define WS_W1B   8192      // bf16 [128][128]                                        32768 B
#define WS_W2GS  40960     // bf16 [20][6][4][64][8] A-frag-swizzled W2g            491520 B
#define WS_B2G   532480    // f32  [20][96]                                           7680 B
#define WS_HWG   540160    // f32  [60][10000]  hwg[(kn*3+g)][b]                   2400000 B

__device__ __forceinline__ unsigned short f2bf(float f) {
    unsigned int u = __float_as_uint(f);
    unsigned int r = (u + 0x7fffu + ((u >> 16) & 1u)) >> 16;
    return (unsigned short)r;
}
__device__ __forceinline__ unsigned int pack2(float a, float b) {
    return (unsigned int)f2bf(a) | ((unsigned int)f2bf(b) << 16);
}

// ---------------- prep ----------------
__global__ __launch_bounds__(256) void prep_kernel(
    const float* __restrict__ W0, const float* __restrict__ b0,
    const float* __restrict__ W1,
    const float* __restrict__ W2, const float* __restrict__ b2,
    const float* __restrict__ h_w,
    unsigned short* __restrict__ w0s, unsigned short* __restrict__ w1b,
    unsigned short* __restrict__ w2gs, float* __restrict__ b2g,
    float* __restrict__ hwg)
{
    const int bx = blockIdx.x, tid = threadIdx.x;
    if (bx < 16) {
        // W2g via per-thread prefix sums (thread=(o,k); 32 ILP loads, each (kn,g)
        // group sum is a register subtraction), stored in A-frag-swizzled order:
        // w2gs[(((kn*6+ct)*4+ka)*64 + quad*16+lq)*8 + j], c=g*32+o=ct*16+lq,
        // k = ka*32+quad*8+j.
        int gid = bx * 256 + tid;
        int o = gid >> 7, k = gid & 127;
        const int ka = k >> 5, quad = (k >> 3) & 3, j = k & 7;
        float pref[32];
        float run = 0.f;
#pragma unroll
        for (int i = 0; i < 32; ++i) {
            run += W2[(size_t)(32 * o + i) * 128 + k];
            pref[i] = run;
        }
#pragma unroll
        for (int kn = 0; kn < 20; ++kn) {
            const int j0 = (32 * kn) / 20;
#pragma unroll
            for (int g = 0; g < 3; ++g) {
                int lo = 20 * (j0 + g) - 32 * kn;     if (lo < 0) lo = 0;
                int hi = 20 * (j0 + g + 1) - 32 * kn; if (hi > 32) hi = 32;
                float v = (hi > lo) ? (pref[hi - 1] - (lo > 0 ? pref[lo - 1] : 0.f)) : 0.f;
                int c = g * 32 + o;
                int ct = c >> 4, lq = c & 15;
                int lane = quad * 16 + lq;
                w2gs[(size_t)(((kn * 6 + ct) * 4 + ka) * 64 + lane) * 8 + j] = f2bf(v);
            }
        }
    } else if (bx == 16) {
        // W0a A-frags: w0s[ct][lane][j] = W0a[ct*16+lq][q*8+j]; col16 = b0, cols>16 = 0
        for (int t = 0; t < 16; ++t) {
            int idx = t * 256 + tid;
            int ct = idx >> 9, lane = (idx >> 3) & 63, j = idx & 7;
            int lq = lane & 15, q = lane >> 4;
            int k = q * 8 + j, o = ct * 16 + lq;
            float v = (k < 16) ? W0[o * 16 + k] : (k == 16 ? b0[o] : 0.f);
            w0s[idx] = f2bf(v);
        }
    } else if (bx <= 32) {
        int base = (bx - 17) * 1024;
        for (int i2 = tid; i2 < 1024; i2 += 256)
            w1b[base + i2] = f2bf(W1[base + i2]);
    } else if (bx == 33) {
        // b2g: 1920 entries
        for (int idx = tid; idx < 1920; idx += 256) {
            int kn = idx / 96, rem = idx - kn * 96;
            int g = rem >> 5, o = rem & 31;
            int j0 = (32 * kn) / 20;
            int lo = 20 * (j0 + g) - 32 * kn;     if (lo < 0) lo = 0;
            int hi = 20 * (j0 + g + 1) - 32 * kn; if (hi > 32) hi = 32;
            float s = 0.f;
            for (int i = lo; i < hi; ++i) s += b2[32 * o + i];
            b2g[idx] = s;
        }
    } else {
        // hwg[(kn*3+g)*10000 + b] = h_w[b*32 + min(j0+g,31)] ; 600000 elems
#pragma unroll
        for (int t = 0; t < 4; ++t) {
            int idx = (bx - 34) * 1024 + t * 256 + tid;
            if (idx < 600000) {
                int kn3 = idx / 10000, b = idx - kn3 * 10000;
                int kn = kn3 / 3, g = kn3 - kn * 3;
                int jv = (32 * kn) / 20 + g; if (jv > 31) jv = 31;
                hwg[idx] = h_w[b * 32 + jv];
            }
        }
    }
}

// ---------------- main fused kernel ----------------
__global__ __launch_bounds__(256, 3) void msg_kernel(
    const float* __restrict__ hwg, const float* __restrict__ e_vw,
    const float* __restrict__ b1v,
    const unsigned short* __restrict__ w0s, const unsigned short* __restrict__ w1b,
    const unsigned short* __restrict__ w2gs, const float* __restrict__ b2g,
    float* __restrict__ out)
{
    __shared__ __align__(16) unsigned short sW1[128 * PADH];   // 34816 B
    __shared__ __align__(16) unsigned short sX[64 * PADH];     // 17408 B
    __shared__ __align__(16) float sB1[128];                   //   512 B
    __shared__ __align__(16) float sB2G[96];                   //   384 B
    // total 53120 B -> 3 blocks/CU (<= 163840/3)

    const int tid = threadIdx.x;
    const int lane = tid & 63, w = tid >> 6;
    const int quad = lane >> 4, lq = lane & 15;
    const int kn = blockIdx.y, chunk = blockIdx.x;
    // active h_w groups for this kn: 2 or 3 (group 2 all-zero when 2)
    const bool three = ((32 * kn) % 20) > 8;

    // ---- stage W1 (+biases) into LDS once per block ----
    {
        const uint4* src = (const uint4*)w1b;
        uint4* dst = (uint4*)sW1;
        for (int i = tid; i < 2048; i += 256) { int r = i >> 4, c = i & 15; dst[r * 17 + c] = src[i]; }
    }
    if (tid < 128) sB1[tid] = b1v[tid];
    if (tid < 96)  sB2G[tid] = b2g[kn * 96 + tid];
    __syncthreads();   // the ONLY barrier

    const int rbase = w * 16;   // wave-private 16-edge strip of sX
    const unsigned short one_bf = 0x3f80;               // bf16(1.0)
    // per-lane bases of the pre-swizzled A-frag tables (global; L1/L2-hot):
    const unsigned short* w0base = w0s + lane * 8;                       // 8 KB table
    const unsigned short* w2base = w2gs + (size_t)kn * 6 * 4 * 512 + lane * 8;

    for (int btile = chunk; btile < 157; btile += NCHUNK) {
        const int e = btile * 64 + rbase + lq;          // this lane's node index

        // ---- B-frag: B[n=lq][k=quad*8+j]; k<16 from e_vw, k==16 -> 1.0 (b0 fold) ----
        union { bf16x8 v; uint4 u; } B;
        B.u = make_uint4(0u, 0u, 0u, 0u);
        if (quad < 2) {
            if (e < NB) {
                const float4* p = (const float4*)(e_vw + ((size_t)e * NNEIGH + kn) * 16 + quad * 8);
                float4 f0 = p[0], f1 = p[1];
                B.u = make_uint4(pack2(f0.x, f0.y), pack2(f0.z, f0.w),
                                 pack2(f1.x, f1.y), pack2(f1.z, f1.w));
            }
        } else if (quad == 2) {
            B.u.x = (unsigned int)one_bf;
        }
        float hw0 = (e < NB) ? hwg[(kn * 3 + 0) * NB + e] : 0.f;
        float hw1 = (e < NB) ? hwg[(kn * 3 + 1) * NB + e] : 0.f;
        float hw2 = (three && e < NB) ? hwg[(kn * 3 + 2) * NB + e] : 0.f;

        // ---- stage A: x0 = relu(W0a @ [E|1]); W0 A-frags from global (L1-hot) ----
#pragma unroll
        for (int ct = 0; ct < 8; ++ct) {
            bf16x8 wf = *(const bf16x8*)(w0base + ct * 512);
            f32x4 acc = {0.f, 0.f, 0.f, 0.f};
            acc = __builtin_amdgcn_mfma_f32_16x16x32_bf16(wf, B.v, acc, 0, 0, 0);
#pragma unroll
            for (int r2 = 0; r2 < 4; ++r2) acc[r2] = acc[r2] > 0.f ? acc[r2] : 0.f;
            uint2 pk = make_uint2(pack2(acc[0], acc[1]), pack2(acc[2], acc[3]));
            *(uint2*)&sX[(rbase + lq) * PADH + ct * 16 + quad * 4] = pk;
        }

        // ---- stage B: x1 = relu(W1 @ x0 + b1), K=128, in-place on sX ----
        {
            bf16x8 xf[4];
#pragma unroll
            for (int ka = 0; ka < 4; ++ka)
                xf[ka] = *(const bf16x8*)&sX[(rbase + lq) * PADH + ka * 32 + quad * 8];
#pragma unroll
            for (int ct = 0; ct < 8; ++ct) {
                f32x4 acc = *(const f32x4*)&sB1[ct * 16 + quad * 4];
#pragma unroll
                for (int ka = 0; ka < 4; ++ka) {
                    bf16x8 wf = *(const bf16x8*)&sW1[(ct * 16 + lq) * PADH + ka * 32 + quad * 8];
                    acc = __builtin_amdgcn_mfma_f32_16x16x32_bf16(wf, xf[ka], acc, 0, 0, 0);
                }
#pragma unroll
                for (int r2 = 0; r2 < 4; ++r2) acc[r2] = acc[r2] > 0.f ? acc[r2] : 0.f;
                uint2 pk = make_uint2(pack2(acc[0], acc[1]), pack2(acc[2], acc[3]));
                *(uint2*)&sX[(rbase + lq) * PADH + ct * 16 + quad * 4] = pk;
            }
        }

        // ---- stage C: G = W2g @ x1 + b2g; W2g A-frags direct from global (L2) ----
        {
            bf16x8 xf[4];
#pragma unroll
            for (int ka = 0; ka < 4; ++ka)
                xf[ka] = *(const bf16x8*)&sX[(rbase + lq) * PADH + ka * 32 + quad * 8];
            f32x4 accC[6];
#pragma unroll
            for (int ct = 0; ct < 4; ++ct) {
                const unsigned short* wp = w2base + (size_t)ct * 4 * 512;
                f32x4 acc = *(const f32x4*)&sB2G[ct * 16 + quad * 4];
#pragma unroll
                for (int ka = 0; ka < 4; ++ka) {
                    bf16x8 wf = *(const bf16x8*)(wp + ka * 512);
                    acc = __builtin_amdgcn_mfma_f32_16x16x32_bf16(wf, xf[ka], acc, 0, 0, 0);
                }
                accC[ct] = acc;
            }
            if (three) {
#pragma unroll
                for (int ct = 4; ct < 6; ++ct) {
                    const unsigned short* wp = w2base + (size_t)ct * 4 * 512;
                    f32x4 acc = *(const f32x4*)&sB2G[ct * 16 + quad * 4];
#pragma unroll
                    for (int ka = 0; ka < 4; ++ka) {
                        bf16x8 wf = *(const bf16x8*)(wp + ka * 512);
                        acc = __builtin_amdgcn_mfma_f32_16x16x32_bf16(wf, xf[ka], acc, 0, 0, 0);
                    }
                    accC[ct] = acc;
                }
            }
            // lane holds G rows c = ct*16+quad*4+r2 for its edge (col=lq);
            // c = g*32 + o, o = half*16+quad*4+r2, ct = g*2+half.
            if (e < NB) {
#pragma unroll
                for (int half = 0; half < 2; ++half) {
                    float4 val;
                    float* vp = &val.x;
#pragma unroll
                    for (int r2 = 0; r2 < 4; ++r2) {
                        float s = hw0 * accC[half][r2] + hw1 * accC[2 + half][r2];
                        if (three) s += hw2 * accC[4 + half][r2];
                        vp[r2] = s;
                    }
                    *(float4*)(out + ((size_t)e * NNEIGH + kn) * 32 + half * 16 + quad * 4) = val;
                }
            }
        }
    }
}

extern "C" void kernel_launch(void* const* d_in, const int* in_sizes, int n_in,
                              void* d_out, int out_size, void* d_ws, size_t ws_size,
                              hipStream_t stream)
{
    // setup_inputs order: h_v, h_w, e_vw, W0, b0, W1, b1, W2, b2  (all float32)
    const float* h_w = (const float*)d_in[1];
    const float* e_vw = (const float*)d_in[2];
    const float* W0 = (const float*)d_in[3];
    const float* b0 = (const float*)d_in[4];
    const float* W1 = (const float*)d_in[5];
    const float* b1 = (const float*)d_in[6];
    const float* W2 = (const float*)d_in[7];
    const float* b2 = (const float*)d_in[8];
    float* out = (float*)d_out;

    char* ws = (char*)d_ws;
    unsigned short* w0s  = (unsigned short*)(ws + WS_W0S);
    unsigned short* w1b  = (unsigned short*)(ws + WS_W1B);
    unsigned short* w2gs = (unsigned short*)(ws + WS_W2GS);
    float*          b2g  = (float*)(ws + WS_B2G);
    float*          hwg  = (float*)(ws + WS_HWG);

    prep_kernel<<<34 + 586, 256, 0, stream>>>(W0, b0, W1, W2, b2, h_w,
                                              w0s, w1b, w2gs, b2g, hwg);
    dim3 grid(NCHUNK, 20);
    msg_kernel<<<grid, 256, 0, stream>>>(hwg, e_vw, b1, w0s, w1b, w2gs, b2g, out);
}

// Round 10
// 153.989 us; speedup vs baseline: 1.5344x; 1.5344x over previous
//
#include <hip/hip_runtime.h>

// MessageFunc: out[e,o] = sum_i (relu-MLP(e_vw)[e] . W2[32o+i] + b2[32o+i]) * hw[e,i]
// hw[e,i] = h_w[b, (32*kn+i)//20], e = b*20+kn. For fixed kn, (32*kn+i)//20 takes
// 2..3 values -> grouped W2g (<=96 cols instead of 1024).
//
// R10: the fused kernel is structurally stuck (R8: allocator expands to 184 regs
// -> 8 waves/CU, 44us latency plateau; R9: any cap -> 84-arch split -> 435MB
// spill). Split at the B/C boundary:
//   K1 = stages A+B -> x1 (bf16, ws). Weights from global pre-swizzled frag
//        tables (L1/L2-hot), LDS = sX transpose buffer only (17.4KB), NO barrier.
//   K2 = stage C + h_w contraction. NO LDS, NO barrier, pure stream.
// Both register-lean -> natural occupancy >= 3 waves/SIMD. Extra x1 traffic
// (~103MB, ~16us HBM) is the price for 2x latency hiding in both halves.

typedef __bf16 bf16x8 __attribute__((ext_vector_type(8)));
typedef float  f32x4  __attribute__((ext_vector_type(4)));

#define NB       10000
#define NNEIGH   20
#define PADH     136       // padded LDS row: 272 B; bank step 4 -> 2-way (free)
#define NBT      157       // edge tiles of 64: 157*64 = 10048 >= 10000
#define EPAD     10048     // padded edges per kn in x1

// ws layout (bytes)
#define WS_W0S   0         // bf16 [8][64][8]  A-frag-swizzled W0a (K=32, col16=b0)   8192 B
#define WS_W1S   8192      // bf16 [8][4][64][8] A-frag-swizzled W1                  32768 B
#define WS_W2GS  40960     // bf16 [20][6][4][64][8] A-frag-swizzled W2g            491520 B
#define WS_B2G   532480    // f32  [20][96]                                           7680 B
#define WS_HWG   540160    // f32  [60][10000]  hwg[(kn*3+g)][b]                   2400000 B
#define WS_X1    2940160   // bf16 [20][10048][128]  x1 activations              51445760 B

__device__ __forceinline__ unsigned short f2bf(float f) {
    unsigned int u = __float_as_uint(f);
    unsigned int r = (u + 0x7fffu + ((u >> 16) & 1u)) >> 16;
    return (unsigned short)r;
}
__device__ __forceinline__ unsigned int pack2(float a, float b) {
    return (unsigned int)f2bf(a) | ((unsigned int)f2bf(b) << 16);
}

// ---------------- prep ----------------
__global__ __launch_bounds__(256) void prep_kernel(
    const float* __restrict__ W0, const float* __restrict__ b0,
    const float* __restrict__ W1,
    const float* __restrict__ W2, const float* __restrict__ b2,
    const float* __restrict__ h_w,
    unsigned short* __restrict__ w0s, unsigned short* __restrict__ w1s,
    unsigned short* __restrict__ w2gs, float* __restrict__ b2g,
    float* __restrict__ hwg)
{
    const int bx = blockIdx.x, tid = threadIdx.x;
    if (bx < 16) {
        // W2g via per-thread prefix sums (thread=(o,k)), stored A-frag-swizzled:
        // w2gs[(((kn*6+ct)*4+ka)*64 + quad*16+lq)*8 + j], c=g*32+o=ct*16+lq,
        // k = ka*32+quad*8+j.
        int gid = bx * 256 + tid;
        int o = gid >> 7, k = gid & 127;
        const int ka = k >> 5, quad = (k >> 3) & 3, j = k & 7;
        float pref[32];
        float run = 0.f;
#pragma unroll
        for (int i = 0; i < 32; ++i) {
            run += W2[(size_t)(32 * o + i) * 128 + k];
            pref[i] = run;
        }
#pragma unroll
        for (int kn = 0; kn < 20; ++kn) {
            const int j0 = (32 * kn) / 20;
#pragma unroll
            for (int g = 0; g < 3; ++g) {
                int lo = 20 * (j0 + g) - 32 * kn;     if (lo < 0) lo = 0;
                int hi = 20 * (j0 + g + 1) - 32 * kn; if (hi > 32) hi = 32;
                float v = (hi > lo) ? (pref[hi - 1] - (lo > 0 ? pref[lo - 1] : 0.f)) : 0.f;
                int c = g * 32 + o;
                int ct = c >> 4, lq = c & 15;
                int lane = quad * 16 + lq;
                w2gs[(size_t)(((kn * 6 + ct) * 4 + ka) * 64 + lane) * 8 + j] = f2bf(v);
            }
        }
    } else if (bx == 16) {
        // W0a A-frags: w0s[ct][lane][j] = W0a[ct*16+lq][q*8+j]; col16 = b0, cols>16 = 0
        for (int t = 0; t < 16; ++t) {
            int idx = t * 256 + tid;
            int ct = idx >> 9, lane = (idx >> 3) & 63, j = idx & 7;
            int lq = lane & 15, q = lane >> 4;
            int k = q * 8 + j, o = ct * 16 + lq;
            float v = (k < 16) ? W0[o * 16 + k] : (k == 16 ? b0[o] : 0.f);
            w0s[idx] = f2bf(v);
        }
    } else if (bx <= 32) {
        // W1 A-frags: w1s[((ct*4+ka)*64+lane)*8+j] = W1[ct*16+lq][ka*32+q*8+j]
        for (int t = 0; t < 4; ++t) {
            int idx = (bx - 17) * 1024 + t * 256 + tid;   // [0,16384)
            int ct = idx >> 11, ka = (idx >> 9) & 3, lane = (idx >> 3) & 63, j = idx & 7;
            int lq = lane & 15, q = lane >> 4;
            w1s[idx] = f2bf(W1[(ct * 16 + lq) * 128 + ka * 32 + q * 8 + j]);
        }
    } else if (bx == 33) {
        // b2g: 1920 entries
        for (int idx = tid; idx < 1920; idx += 256) {
            int kn = idx / 96, rem = idx - kn * 96;
            int g = rem >> 5, o = rem & 31;
            int j0 = (32 * kn) / 20;
            int lo = 20 * (j0 + g) - 32 * kn;     if (lo < 0) lo = 0;
            int hi = 20 * (j0 + g + 1) - 32 * kn; if (hi > 32) hi = 32;
            float s = 0.f;
            for (int i = lo; i < hi; ++i) s += b2[32 * o + i];
            b2g[idx] = s;
        }
    } else {
        // hwg[(kn*3+g)*10000 + b] = h_w[b*32 + min(j0+g,31)] ; 600000 elems
#pragma unroll
        for (int t = 0; t < 4; ++t) {
            int idx = (bx - 34) * 1024 + t * 256 + tid;
            if (idx < 600000) {
                int kn3 = idx / 10000, b = idx - kn3 * 10000;
                int kn = kn3 / 3, g = kn3 - kn * 3;
                int jv = (32 * kn) / 20 + g; if (jv > 31) jv = 31;
                hwg[idx] = h_w[b * 32 + jv];
            }
        }
    }
}

// ---------------- K1: stages A+B -> x1 ----------------
__global__ __launch_bounds__(256) void k1_kernel(
    const float* __restrict__ e_vw, const float* __restrict__ b1v,
    const unsigned short* __restrict__ w0s, const unsigned short* __restrict__ w1s,
    unsigned short* __restrict__ x1)
{
    __shared__ __align__(16) unsigned short sX[64 * PADH];   // 17408 B, wave-private strips

    const int tid = threadIdx.x;
    const int lane = tid & 63, w = tid >> 6;
    const int quad = lane >> 4, lq = lane & 15;
    const int kn = blockIdx.y;
    const int rbase = w * 16;
    const int e = blockIdx.x * 64 + rbase + lq;          // this lane's node index
    const unsigned short one_bf = 0x3f80;                // bf16(1.0)

    const unsigned short* w0base = w0s + lane * 8;       // 8 KB table, L1-hot
    const unsigned short* w1base = w1s + lane * 8;       // 32 KB table, L2-hot

    // ---- B-frag: B[n=lq][k=quad*8+j]; k<16 from e_vw, k==16 -> 1.0 (b0 fold) ----
    union { bf16x8 v; uint4 u; } B;
    B.u = make_uint4(0u, 0u, 0u, 0u);
    if (quad < 2) {
        if (e < NB) {
            const float4* p = (const float4*)(e_vw + ((size_t)e * NNEIGH + kn) * 16 + quad * 8);
            float4 f0 = p[0], f1 = p[1];
            B.u = make_uint4(pack2(f0.x, f0.y), pack2(f0.z, f0.w),
                             pack2(f1.x, f1.y), pack2(f1.z, f1.w));
        }
    } else if (quad == 2) {
        B.u.x = (unsigned int)one_bf;
    }

    // ---- stage A: x0 = relu(W0a @ [E|1]) -> sX (wave-private, no barrier) ----
#pragma unroll
    for (int ct = 0; ct < 8; ++ct) {
        bf16x8 wf = *(const bf16x8*)(w0base + ct * 512);
        f32x4 acc = {0.f, 0.f, 0.f, 0.f};
        acc = __builtin_amdgcn_mfma_f32_16x16x32_bf16(wf, B.v, acc, 0, 0, 0);
#pragma unroll
        for (int r2 = 0; r2 < 4; ++r2) acc[r2] = acc[r2] > 0.f ? acc[r2] : 0.f;
        uint2 pk = make_uint2(pack2(acc[0], acc[1]), pack2(acc[2], acc[3]));
        *(uint2*)&sX[(rbase + lq) * PADH + ct * 16 + quad * 4] = pk;
    }

    // ---- stage B: x1 = relu(W1 @ x0 + b1) -> global x1 (bf16 [kn][EPAD][128]) ----
    {
        bf16x8 xf[4];
#pragma unroll
        for (int ka = 0; ka < 4; ++ka)
            xf[ka] = *(const bf16x8*)&sX[(rbase + lq) * PADH + ka * 32 + quad * 8];
        unsigned short* xout = x1 + ((size_t)kn * EPAD + e) * 128;
#pragma unroll
        for (int ct = 0; ct < 8; ++ct) {
            f32x4 acc = *(const f32x4*)(b1v + ct * 16 + quad * 4);
#pragma unroll
            for (int ka = 0; ka < 4; ++ka) {
                bf16x8 wf = *(const bf16x8*)(w1base + (ct * 4 + ka) * 512);
                acc = __builtin_amdgcn_mfma_f32_16x16x32_bf16(wf, xf[ka], acc, 0, 0, 0);
            }
#pragma unroll
            for (int r2 = 0; r2 < 4; ++r2) acc[r2] = acc[r2] > 0.f ? acc[r2] : 0.f;
            // lane holds features ct*16+quad*4..+3 of edge lq (col=lq)
            *(uint2*)(xout + ct * 16 + quad * 4) =
                make_uint2(pack2(acc[0], acc[1]), pack2(acc[2], acc[3]));
        }
    }
}

// ---------------- K2: stage C + h_w contraction (no LDS, no barrier) ----------------
__global__ __launch_bounds__(256) void k2_kernel(
    const float* __restrict__ hwg, const unsigned short* __restrict__ x1,
    const unsigned short* __restrict__ w2gs, const float* __restrict__ b2g,
    float* __restrict__ out)
{
    const int tid = threadIdx.x;
    const int lane = tid & 63, w = tid >> 6;
    const int quad = lane >> 4, lq = lane & 15;
    const int kn = blockIdx.y;
    const int e = blockIdx.x * 64 + w * 16 + lq;         // this lane's node index
    const bool three = ((32 * kn) % 20) > 8;             // 2 or 3 active h_w groups

    const unsigned short* w2base = w2gs + (size_t)kn * 6 * 4 * 512 + lane * 8;

    // ---- x1 B-frags straight from global ----
    bf16x8 xf[4];
    const unsigned short* xin = x1 + ((size_t)kn * EPAD + e) * 128;
#pragma unroll
    for (int ka = 0; ka < 4; ++ka)
        xf[ka] = *(const bf16x8*)(xin + ka * 32 + quad * 8);

    float hw0 = (e < NB) ? hwg[(kn * 3 + 0) * NB + e] : 0.f;
    float hw1 = (e < NB) ? hwg[(kn * 3 + 1) * NB + e] : 0.f;
    float hw2 = (three && e < NB) ? hwg[(kn * 3 + 2) * NB + e] : 0.f;

    f32x4 accC[6];
#pragma unroll
    for (int ct = 0; ct < 4; ++ct) {
        const unsigned short* wp = w2base + (size_t)ct * 4 * 512;
        f32x4 acc = *(const f32x4*)(b2g + kn * 96 + ct * 16 + quad * 4);
#pragma unroll
        for (int ka = 0; ka < 4; ++ka) {
            bf16x8 wf = *(const bf16x8*)(wp + ka * 512);
            acc = __builtin_amdgcn_mfma_f32_16x16x32_bf16(wf, xf[ka], acc, 0, 0, 0);
        }
        accC[ct] = acc;
    }
    if (three) {
#pragma unroll
        for (int ct = 4; ct < 6; ++ct) {
            const unsigned short* wp = w2base + (size_t)ct * 4 * 512;
            f32x4 acc = *(const f32x4*)(b2g + kn * 96 + ct * 16 + quad * 4);
#pragma unroll
            for (int ka = 0; ka < 4; ++ka) {
                bf16x8 wf = *(const bf16x8*)(wp + ka * 512);
                acc = __builtin_amdgcn_mfma_f32_16x16x32_bf16(wf, xf[ka], acc, 0, 0, 0);
            }
            accC[ct] = acc;
        }
    }
    // lane holds G rows c = ct*16+quad*4+r2 for its edge (col=lq);
    // c = g*32 + o, o = half*16+quad*4+r2, ct = g*2+half.
    if (e < NB) {
#pragma unroll
        for (int half = 0; half < 2; ++half) {
            float4 val;
            float* vp = &val.x;
#pragma unroll
            for (int r2 = 0; r2 < 4; ++r2) {
                float s = hw0 * accC[half][r2] + hw1 * accC[2 + half][r2];
                if (three) s += hw2 * accC[4 + half][r2];
                vp[r2] = s;
            }
            *(float4*)(out + ((size_t)e * NNEIGH + kn) * 32 + half * 16 + quad * 4) = val;
        }
    }
}

extern "C" void kernel_launch(void* const* d_in, const int* in_sizes, int n_in,
                              void* d_out, int out_size, void* d_ws, size_t ws_size,
                              hipStream_t stream)
{
    // setup_inputs order: h_v, h_w, e_vw, W0, b0, W1, b1, W2, b2  (all float32)
    const float* h_w = (const float*)d_in[1];
    const float* e_vw = (const float*)d_in[2];
    const float* W0 = (const float*)d_in[3];
    const float* b0 = (const float*)d_in[4];
    const float* W1 = (const float*)d_in[5];
    const float* b1 = (const float*)d_in[6];
    const float* W2 = (const float*)d_in[7];
    const float* b2 = (const float*)d_in[8];
    float* out = (float*)d_out;

    char* ws = (char*)d_ws;
    unsigned short* w0s  = (unsigned short*)(ws + WS_W0S);
    unsigned short* w1s  = (unsigned short*)(ws + WS_W1S);
    unsigned short* w2gs = (unsigned short*)(ws + WS_W2GS);
    float*          b2g  = (float*)(ws + WS_B2G);
    float*          hwg  = (float*)(ws + WS_HWG);
    unsigned short* x1   = (unsigned short*)(ws + WS_X1);

    prep_kernel<<<620, 256, 0, stream>>>(W0, b0, W1, W2, b2, h_w,
                                         w0s, w1s, w2gs, b2g, hwg);
    dim3 grid(NBT, 20);
    k1_kernel<<<grid, 256, 0, stream>>>(e_vw, b1, w0s, w1s, x1);
    k2_kernel<<<grid, 256, 0, stream>>>(hwg, x1, w2gs, b2g, out);
}

// Round 11
// 139.168 us; speedup vs baseline: 1.6978x; 1.1065x over previous
//
#include <hip/hip_runtime.h>

// MessageFunc: out[e,o] = sum_i (relu-MLP(e_vw)[e] . W2[32o+i] + b2[32o+i]) * hw[e,i]
// hw[e,i] = h_w[b, (32*kn+i)//20], e = b*20+kn. For fixed kn, (32*kn+i)//20 takes
// 2..3 values -> grouped W2g (<=96 cols instead of 1024).
//
// R11 = R10 split + btile loops (the missing amortization):
//   k1 (A+B->x1): W1 in LDS flat pre-swizzled (contiguous 16B/lane b128 reads,
//      optimal LDS pattern), w0f in 32 regs, ~4 btiles/block w/ e_vw prefetch.
//      LDS 50.2KB -> 3 blocks/CU; lean regs (~115).
//   k2 (C+hw): NO LDS/barriers; W2g frags in 96 regs loaded once per block
//      (safe here: total ledger ~160), ~4 btiles/block, 4 coalesced x1 loads +
//      16-24 reg-only MFMA + stores. HBM-bound floor ~12us.
// R10 failure: 1 btile/block => every wave re-fetched 24-32KB of weight frags
// from L2 and had one unprefetchable serial chain.

typedef __bf16 bf16x8 __attribute__((ext_vector_type(8)));
typedef float  f32x4  __attribute__((ext_vector_type(4)));

#define NB       10000
#define NNEIGH   20
#define PADH     136       // padded LDS row for sX: 272 B; bank step 4 -> 2-way (free)
#define NCHUNK   39        // blocks per kn; 780 blocks; 4-5 btiles each
#define NBT      157
#define EPAD     10048     // padded edges per kn in x1

// ws layout (bytes)
#define WS_W0S   0         // bf16 [8][64][8]  A-frag-swizzled W0a (K=32, col16=b0)   8192 B
#define WS_W1S   8192      // bf16 [8][4][64][8] A-frag-swizzled W1                  32768 B
#define WS_W2GS  40960     // bf16 [20][6][4][64][8] A-frag-swizzled W2g            491520 B
#define WS_B2G   532480    // f32  [20][96]                                           7680 B
#define WS_HWG   540160    // f32  [60][10000]  hwg[(kn*3+g)][b]                   2400000 B
#define WS_X1    2940160   // bf16 [20][10048][128]  x1 activations              51445760 B

__device__ __forceinline__ unsigned short f2bf(float f) {
    unsigned int u = __float_as_uint(f);
    unsigned int r = (u + 0x7fffu + ((u >> 16) & 1u)) >> 16;
    return (unsigned short)r;
}
__device__ __forceinline__ unsigned int pack2(float a, float b) {
    return (unsigned int)f2bf(a) | ((unsigned int)f2bf(b) << 16);
}

// ---------------- prep ----------------
__global__ __launch_bounds__(256) void prep_kernel(
    const float* __restrict__ W0, const float* __restrict__ b0,
    const float* __restrict__ W1,
    const float* __restrict__ W2, const float* __restrict__ b2,
    const float* __restrict__ h_w,
    unsigned short* __restrict__ w0s, unsigned short* __restrict__ w1s,
    unsigned short* __restrict__ w2gs, float* __restrict__ b2g,
    float* __restrict__ hwg)
{
    const int bx = blockIdx.x, tid = threadIdx.x;
    if (bx < 16) {
        // W2g via per-thread prefix sums (thread=(o,k)), stored A-frag-swizzled:
        // w2gs[(((kn*6+ct)*4+ka)*64 + quad*16+lq)*8 + j], c=g*32+o=ct*16+lq,
        // k = ka*32+quad*8+j.
        int gid = bx * 256 + tid;
        int o = gid >> 7, k = gid & 127;
        const int ka = k >> 5, quad = (k >> 3) & 3, j = k & 7;
        float pref[32];
        float run = 0.f;
#pragma unroll
        for (int i = 0; i < 32; ++i) {
            run += W2[(size_t)(32 * o + i) * 128 + k];
            pref[i] = run;
        }
#pragma unroll
        for (int kn = 0; kn < 20; ++kn) {
            const int j0 = (32 * kn) / 20;
#pragma unroll
            for (int g = 0; g < 3; ++g) {
                int lo = 20 * (j0 + g) - 32 * kn;     if (lo < 0) lo = 0;
                int hi = 20 * (j0 + g + 1) - 32 * kn; if (hi > 32) hi = 32;
                float v = (hi > lo) ? (pref[hi - 1] - (lo > 0 ? pref[lo - 1] : 0.f)) : 0.f;
                int c = g * 32 + o;
                int ct = c >> 4, lq = c & 15;
                int lane = quad * 16 + lq;
                w2gs[(size_t)(((kn * 6 + ct) * 4 + ka) * 64 + lane) * 8 + j] = f2bf(v);
            }
        }
    } else if (bx == 16) {
        // W0a A-frags: w0s[ct][lane][j] = W0a[ct*16+lq][q*8+j]; col16 = b0, cols>16 = 0
        for (int t = 0; t < 16; ++t) {
            int idx = t * 256 + tid;
            int ct = idx >> 9, lane = (idx >> 3) & 63, j = idx & 7;
            int lq = lane & 15, q = lane >> 4;
            int k = q * 8 + j, o = ct * 16 + lq;
            float v = (k < 16) ? W0[o * 16 + k] : (k == 16 ? b0[o] : 0.f);
            w0s[idx] = f2bf(v);
        }
    } else if (bx <= 32) {
        // W1 A-frags: w1s[((ct*4+ka)*64+lane)*8+j] = W1[ct*16+lq][ka*32+q*8+j]
        for (int t = 0; t < 4; ++t) {
            int idx = (bx - 17) * 1024 + t * 256 + tid;   // [0,16384)
            int ct = idx >> 11, ka = (idx >> 9) & 3, lane = (idx >> 3) & 63, j = idx & 7;
            int lq = lane & 15, q = lane >> 4;
            w1s[idx] = f2bf(W1[(ct * 16 + lq) * 128 + ka * 32 + q * 8 + j]);
        }
    } else if (bx == 33) {
        // b2g: 1920 entries (zero-width groups -> 0)
        for (int idx = tid; idx < 1920; idx += 256) {
            int kn = idx / 96, rem = idx - kn * 96;
            int g = rem >> 5, o = rem & 31;
            int j0 = (32 * kn) / 20;
            int lo = 20 * (j0 + g) - 32 * kn;     if (lo < 0) lo = 0;
            int hi = 20 * (j0 + g + 1) - 32 * kn; if (hi > 32) hi = 32;
            float s = 0.f;
            for (int i = lo; i < hi; ++i) s += b2[32 * o + i];
            b2g[idx] = s;
        }
    } else {
        // hwg[(kn*3+g)*10000 + b] = h_w[b*32 + min(j0+g,31)] ; 600000 elems
#pragma unroll
        for (int t = 0; t < 4; ++t) {
            int idx = (bx - 34) * 1024 + t * 256 + tid;
            if (idx < 600000) {
                int kn3 = idx / 10000, b = idx - kn3 * 10000;
                int kn = kn3 / 3, g = kn3 - kn * 3;
                int jv = (32 * kn) / 20 + g; if (jv > 31) jv = 31;
                hwg[idx] = h_w[b * 32 + jv];
            }
        }
    }
}

// ---------------- K1: stages A+B -> x1 (loops over btiles) ----------------
__global__ __launch_bounds__(256) void k1_kernel(
    const float* __restrict__ e_vw, const float* __restrict__ b1v,
    const unsigned short* __restrict__ w0s, const unsigned short* __restrict__ w1s,
    unsigned short* __restrict__ x1)
{
    __shared__ __align__(16) unsigned short sW1f[16384];     // 32768 B, flat frag order
    __shared__ __align__(16) unsigned short sX[64 * PADH];   // 17408 B, wave-private

    const int tid = threadIdx.x;
    const int lane = tid & 63, w = tid >> 6;
    const int quad = lane >> 4, lq = lane & 15;
    const int kn = blockIdx.y, chunk = blockIdx.x;
    const int rbase = w * 16;
    const unsigned short one_bf = 0x3f80;

    // stage W1 frags into LDS flat (identity copy; reads are 16B/lane contiguous)
    {
        const uint4* src = (const uint4*)w1s;
        uint4* dst = (uint4*)sW1f;
        for (int i = tid; i < 2048; i += 256) dst[i] = src[i];
    }
    // W0 A-frags in registers (32 VGPRs)
    bf16x8 w0f[8];
#pragma unroll
    for (int ct = 0; ct < 8; ++ct)
        w0f[ct] = *(const bf16x8*)(w0s + (ct * 64 + lane) * 8);
    __syncthreads();   // the ONLY barrier

    const unsigned short* sW1base = sW1f + lane * 8;

    // prologue: prefetch first btile's e_vw
    float4 f0, f1;
    {
        const int e = chunk * 64 + rbase + lq;
        if (quad < 2 && e < NB) {
            const float4* p = (const float4*)(e_vw + ((size_t)e * NNEIGH + kn) * 16 + quad * 8);
            f0 = p[0]; f1 = p[1];
        }
    }

    for (int btile = chunk; btile < NBT; btile += NCHUNK) {
        const int e = btile * 64 + rbase + lq;

        // B-frag: B[n=lq][k=quad*8+j]; k<16 = e_vw, k==16 -> 1.0 (b0 fold)
        union { bf16x8 v; uint4 u; } B;
        B.u = make_uint4(0u, 0u, 0u, 0u);
        if (quad < 2) {
            if (e < NB)
                B.u = make_uint4(pack2(f0.x, f0.y), pack2(f0.z, f0.w),
                                 pack2(f1.x, f1.y), pack2(f1.z, f1.w));
        } else if (quad == 2) {
            B.u.x = (unsigned int)one_bf;
        }

        // prefetch next btile's e_vw (overlaps stages A+B)
        {
            const int ne = (btile + NCHUNK) * 64 + rbase + lq;
            if (btile + NCHUNK < NBT && quad < 2 && ne < NB) {
                const float4* p = (const float4*)(e_vw + ((size_t)ne * NNEIGH + kn) * 16 + quad * 8);
                f0 = p[0]; f1 = p[1];
            }
        }

        // stage A: x0 = relu(W0a @ [E|1]) -> sX (wave-private strip)
#pragma unroll
        for (int ct = 0; ct < 8; ++ct) {
            f32x4 acc = {0.f, 0.f, 0.f, 0.f};
            acc = __builtin_amdgcn_mfma_f32_16x16x32_bf16(w0f[ct], B.v, acc, 0, 0, 0);
#pragma unroll
            for (int r2 = 0; r2 < 4; ++r2) acc[r2] = acc[r2] > 0.f ? acc[r2] : 0.f;
            uint2 pk = make_uint2(pack2(acc[0], acc[1]), pack2(acc[2], acc[3]));
            *(uint2*)&sX[(rbase + lq) * PADH + ct * 16 + quad * 4] = pk;
        }

        // stage B: x1 = relu(W1 @ x0 + b1) -> global x1 (bf16 [kn][EPAD][128])
        {
            bf16x8 xf[4];
#pragma unroll
            for (int ka = 0; ka < 4; ++ka)
                xf[ka] = *(const bf16x8*)&sX[(rbase + lq) * PADH + ka * 32 + quad * 8];
            unsigned short* xout = x1 + ((size_t)kn * EPAD + e) * 128;
#pragma unroll
            for (int ct = 0; ct < 8; ++ct) {
                f32x4 acc = *(const f32x4*)(b1v + ct * 16 + quad * 4);
#pragma unroll
                for (int ka = 0; ka < 4; ++ka) {
                    bf16x8 wf = *(const bf16x8*)(sW1base + (ct * 4 + ka) * 512);
                    acc = __builtin_amdgcn_mfma_f32_16x16x32_bf16(wf, xf[ka], acc, 0, 0, 0);
                }
#pragma unroll
                for (int r2 = 0; r2 < 4; ++r2) acc[r2] = acc[r2] > 0.f ? acc[r2] : 0.f;
                *(uint2*)(xout + ct * 16 + quad * 4) =
                    make_uint2(pack2(acc[0], acc[1]), pack2(acc[2], acc[3]));
            }
        }
    }
}

// ---------------- K2: stage C + h_w contraction (no LDS, no barrier) ----------------
__global__ __launch_bounds__(256) void k2_kernel(
    const float* __restrict__ hwg, const unsigned short* __restrict__ x1,
    const unsigned short* __restrict__ w2gs, const float* __restrict__ b2g,
    float* __restrict__ out)
{
    const int tid = threadIdx.x;
    const int lane = tid & 63, w = tid >> 6;
    const int quad = lane >> 4, lq = lane & 15;
    const int kn = blockIdx.y, chunk = blockIdx.x;
    const int rbase = w * 16;
    const bool three = ((32 * kn) % 20) > 8;

    // W2g frags register-resident for the whole block (96 or 64 VGPRs)
    const unsigned short* w2base = w2gs + (size_t)kn * 6 * 4 * 512 + lane * 8;
    bf16x8 w2f[6][4];
#pragma unroll
    for (int ct = 0; ct < 4; ++ct)
#pragma unroll
        for (int ka = 0; ka < 4; ++ka)
            w2f[ct][ka] = *(const bf16x8*)(w2base + (size_t)(ct * 4 + ka) * 512);
    if (three) {
#pragma unroll
        for (int ct = 4; ct < 6; ++ct)
#pragma unroll
            for (int ka = 0; ka < 4; ++ka)
                w2f[ct][ka] = *(const bf16x8*)(w2base + (size_t)(ct * 4 + ka) * 512);
    }
    // b2g C-inits register-resident (24 regs)
    f32x4 b2r[6];
#pragma unroll
    for (int ct = 0; ct < 6; ++ct)
        b2r[ct] = *(const f32x4*)(b2g + kn * 96 + ct * 16 + quad * 4);

    for (int btile = chunk; btile < NBT; btile += NCHUNK) {
        const int e = btile * 64 + rbase + lq;

        // x1 B-frags: coalesced (16 rows x 256 B contiguous per wave)
        bf16x8 xf[4];
        const unsigned short* xin = x1 + ((size_t)kn * EPAD + e) * 128;
#pragma unroll
        for (int ka = 0; ka < 4; ++ka)
            xf[ka] = *(const bf16x8*)(xin + ka * 32 + quad * 8);

        float hw0 = (e < NB) ? hwg[(kn * 3 + 0) * NB + e] : 0.f;
        float hw1 = (e < NB) ? hwg[(kn * 3 + 1) * NB + e] : 0.f;
        float hw2 = (three && e < NB) ? hwg[(kn * 3 + 2) * NB + e] : 0.f;

        f32x4 accC[6];
#pragma unroll
        for (int ct = 0; ct < 4; ++ct) {
            f32x4 acc = b2r[ct];
#pragma unroll
            for (int ka = 0; ka < 4; ++ka)
                acc = __builtin_amdgcn_mfma_f32_16x16x32_bf16(w2f[ct][ka], xf[ka], acc, 0, 0, 0);
            accC[ct] = acc;
        }
        if (three) {
#pragma unroll
            for (int ct = 4; ct < 6; ++ct) {
                f32x4 acc = b2r[ct];
#pragma unroll
                for (int ka = 0; ka < 4; ++ka)
                    acc = __builtin_amdgcn_mfma_f32_16x16x32_bf16(w2f[ct][ka], xf[ka], acc, 0, 0, 0);
                accC[ct] = acc;
            }
        }
        // lane holds G rows c = ct*16+quad*4+r2 for its edge (col=lq);
        // c = g*32 + o, o = half*16+quad*4+r2, ct = g*2+half.
        if (e < NB) {
#pragma unroll
            for (int half = 0; half < 2; ++half) {
                float4 val;
                float* vp = &val.x;
#pragma unroll
                for (int r2 = 0; r2 < 4; ++r2) {
                    float s = hw0 * accC[half][r2] + hw1 * accC[2 + half][r2];
                    if (three) s += hw2 * accC[4 + half][r2];
                    vp[r2] = s;
                }
                *(float4*)(out + ((size_t)e * NNEIGH + kn) * 32 + half * 16 + quad * 4) = val;
            }
        }
    }
}

extern "C" void kernel_launch(void* const* d_in, const int* in_sizes, int n_in,
                              void* d_out, int out_size, void* d_ws, size_t ws_size,
                              hipStream_t stream)
{
    // setup_inputs order: h_v, h_w, e_vw, W0, b0, W1, b1, W2, b2  (all float32)
    const float* h_w = (const float*)d_in[1];
    const float* e_vw = (const float*)d_in[2];
    const float* W0 = (const float*)d_in[3];
    const float* b0 = (const float*)d_in[4];
    const float* W1 = (const float*)d_in[5];
    const float* b1 = (const float*)d_in[6];
    const float* W2 = (const float*)d_in[7];
    const float* b2 = (const float*)d_in[8];
    float* out = (float*)d_out;

    char* ws = (char*)d_ws;
    unsigned short* w0s  = (unsigned short*)(ws + WS_W0S);
    unsigned short* w1s  = (unsigned short*)(ws + WS_W1S);
    unsigned short* w2gs = (unsigned short*)(ws + WS_W2GS);
    float*          b2g  = (float*)(ws + WS_B2G);
    float*          hwg  = (float*)(ws + WS_HWG);
    unsigned short* x1   = (unsigned short*)(ws + WS_X1);

    prep_kernel<<<620, 256, 0, stream>>>(W0, b0, W1, W2, b2, h_w,
                                         w0s, w1s, w2gs, b2g, hwg);
    dim3 grid(NCHUNK, 20);
    k1_kernel<<<grid, 256, 0, stream>>>(e_vw, b1, w0s, w1s, x1);
    k2_kernel<<<grid, 256, 0, stream>>>(hwg, x1, w2gs, b2g, out);
}